// Round 21
// baseline (580.266 us; speedup 1.0000x reference)
//
#include <hip/hip_runtime.h>
#include <math.h>

#define DIV_UP(a,b) (((a)+(b)-1)/(b))

static constexpr int Bb = 4, Tt = 256, Mm = 512, Dd = 1024, Vv = 50257;
static constexpr int NN = Bb * Tt;   // 1024 flattened (b,t) rows

typedef __attribute__((ext_vector_type(8))) short short8v;
typedef __attribute__((ext_vector_type(4))) float float4v;
typedef unsigned short ushort;

// fp32 -> bf16 RNE (bit trick, branchless)
static __device__ __forceinline__ ushort f2bf(float f) {
    unsigned u = __float_as_uint(f);
    u += 0x7FFFu + ((u >> 16) & 1u);
    return (ushort)(u >> 16);
}
static __device__ __forceinline__ float bf2f(ushort h) {
    return __uint_as_float(((unsigned)h) << 16);
}

// async 16B global -> LDS (wave-uniform base + lane*16 dest)
static __device__ __forceinline__ void gload16(const void* g, void* l) {
    __builtin_amdgcn_global_load_lds(
        (const __attribute__((address_space(1))) unsigned int*)g,
        (__attribute__((address_space(3))) unsigned int*)l, 16, 0, 0);
}

// ---- fused prep: all input casts in ONE launch ------------------------------
static constexpr long PN0 = (long)NN * Dd / 8;
static constexpr long PN1 = (long)Bb * Mm * Dd / 8;
static constexpr long PN2 = (long)Dd * 2 * Dd / 8;
static constexpr long PN3 = (long)Vv * Dd / 8;
static constexpr long PTOT = PN0 + PN1 + PN2 + PN3;

__launch_bounds__(256)
__global__ void prep_all(const float* __restrict__ dec, ushort* __restrict__ A16,
                         ushort* __restrict__ dec_lo,
                         const float* __restrict__ mem, ushort* __restrict__ mem_hi,
                         ushort* __restrict__ mem_lo,
                         const float* __restrict__ Wd, ushort* __restrict__ Wd16,
                         const float* __restrict__ Wo, ushort* __restrict__ B16)
{
    for (long i = blockIdx.x * 256 + threadIdx.x; i < PTOT; i += (long)gridDim.x * 256) {
        const float* src; ushort* hi; ushort* lo = nullptr; long off;
        if (i < PN0)                  { src = dec; hi = A16;    lo = dec_lo; off = i; }
        else if (i < PN0 + PN1)       { src = mem; hi = mem_hi; lo = mem_lo; off = i - PN0; }
        else if (i < PN0 + PN1 + PN2) { src = Wd;  hi = Wd16;   off = i - PN0 - PN1; }
        else                          { src = Wo;  hi = B16;    off = i - PN0 - PN1 - PN2; }

        const float4 v0 = *(const float4*)&src[off * 8];
        const float4 v1 = *(const float4*)&src[off * 8 + 4];
        short8v th, tl;
        float vs[8] = {v0.x, v0.y, v0.z, v0.w, v1.x, v1.y, v1.z, v1.w};
#pragma unroll
        for (int q = 0; q < 8; ++q) {
            ushort h = f2bf(vs[q]);
            th[q] = h;
            tl[q] = f2bf(vs[q] - bf2f(h));
        }
        *(short8v*)&hi[off * 8] = th;
        if (lo) *(short8v*)&lo[off * 8] = tl;
    }
}

// ---- batched transpose: in[b] R x C fp32 -> out[b] C x R bf16 (hi, opt lo) --
__launch_bounds__(256)
__global__ void transpose_split(const float* __restrict__ in, ushort* __restrict__ oh,
                                ushort* __restrict__ ol, int R, int C)
{
    __shared__ float t[32][33];
    const int bz = blockIdx.z;
    in += (long)bz * R * C;
    oh += (long)bz * R * C;
    if (ol) ol += (long)bz * R * C;
    const int tx = threadIdx.x & 31, ty = threadIdx.x >> 5;
    const int r0 = blockIdx.y * 32, c0 = blockIdx.x * 32;
#pragma unroll
    for (int k = 0; k < 4; ++k)
        t[ty + k * 8][tx] = in[(long)(r0 + ty + k * 8) * C + c0 + tx];
    __syncthreads();
#pragma unroll
    for (int k = 0; k < 4; ++k) {
        float v = t[tx][ty + k * 8];
        ushort h = f2bf(v);
        long o = (long)(c0 + ty + k * 8) * R + r0 + tx;
        oh[o] = h;
        if (ol) ol[o] = f2bf(v - bf2f(h));
    }
}

// ---------------------------------------------------------------------------
// Unified bf16 MFMA GEMM (NT): C[i,j] = sum_k A[i,k]*B[j,k]
// Proven 2-buffer drain loop (K5 structure), BK=32, 4-slot XOR source swizzle.
// SPLIT: 3-pass split-bf16 (Ah*Bh + Ah*Bl + Al*Bh).
// MREP: wave M-fragments; block tile = (MREP*32) x 128.
// epi: 0 = fp32 C; 2 = pgacc[i] += sum tanh(x+b)*Wg; 3 = split hi/lo bf16 C;
//      4 = bf16 C write. (epi=1 lives in the dedicated gemm_logits kernel.)
// ---------------------------------------------------------------------------
template<bool SPLIT, int MREP>
__launch_bounds__(256)
__global__ void gemm_mx(const ushort* __restrict__ Ah, const ushort* __restrict__ Al,
                        const ushort* __restrict__ Bh, const ushort* __restrict__ Bl,
                        const ushort* __restrict__ A2, int ksplit, int lda2,
                        const float* __restrict__ bias,
                        float* __restrict__ Cf, ushort* __restrict__ C16,
                        float* __restrict__ aux, const float* __restrict__ Wg,
                        int Ncols, int K, int lda, int ldb, int ldc,
                        long sA, long sB, long sC, int epi)
{
    constexpr int BM    = MREP * 32;        // block rows
    constexpr int ATILE = BM * 32;          // ushorts per A tile (BM x 32)
    constexpr int BTILE = 4096;             // 128 x 32
    constexpr int BUF   = (SPLIT ? 2 : 1) * (ATILE + BTILE);
    __shared__ __align__(16) ushort lds[2 * BUF];

    const int jt = blockIdx.x, mt = blockIdx.y, bz = blockIdx.z;

    const int tid  = threadIdx.x;
    const int lane = tid & 63;
    const int wave = tid >> 6;
    const int mw = (wave >> 1) * (MREP * 16), nw = (wave & 1) * 64;
    const int i0 = mt * BM, j0 = jt * 128;

    const int srow = tid >> 2;                              // 0..63
    const int soff = ((tid & 3) ^ ((srow >> 1) & 3)) * 8;   // swizzled source slot

    const long Ab = (long)bz * sA;
    const long Bz = (long)bz * sB;
    const long ar0 = i0 + srow, ar1 = i0 + 64 + srow;       // ar1 used iff MREP==4
    long br0 = j0 + srow;      if (br0 > Ncols - 1) br0 = Ncols - 1;
    long br1 = j0 + 64 + srow; if (br1 > Ncols - 1) br1 = Ncols - 1;

    const int NT = K >> 5;
    const int fr = lane & 15;
    const int rdsw = ((lane >> 4) ^ ((fr >> 1) & 3)) * 8;   // swizzled read slot

    float4v acc[MREP][4];
#pragma unroll
    for (int m = 0; m < MREP; ++m)
#pragma unroll
        for (int n = 0; n < 4; ++n) acc[m][n] = (float4v){0.f, 0.f, 0.f, 0.f};

    auto STAGE = [&](int buf, int kc) {
        ushort* base = lds + buf * BUF;
        if constexpr (SPLIT) {
            const ushort* pAh = Ah + Ab; const ushort* pAl = Al + Ab;
            const ushort* pBh = Bh + Bz; const ushort* pBl = Bl + Bz;
            gload16(&pAh[ar0 * lda + kc + soff], base + tid * 8);
            if constexpr (MREP == 4)
                gload16(&pAh[ar1 * lda + kc + soff], base + 2048 + tid * 8);
            ushort* bAl = base + ATILE;
            gload16(&pAl[ar0 * lda + kc + soff], bAl + tid * 8);
            if constexpr (MREP == 4)
                gload16(&pAl[ar1 * lda + kc + soff], bAl + 2048 + tid * 8);
            ushort* bBh = base + 2 * ATILE;
            gload16(&pBh[br0 * ldb + kc + soff], bBh + tid * 8);
            gload16(&pBh[br1 * ldb + kc + soff], bBh + 2048 + tid * 8);
            ushort* bBl = bBh + BTILE;
            gload16(&pBl[br0 * ldb + kc + soff], bBl + tid * 8);
            gload16(&pBl[br1 * ldb + kc + soff], bBl + 2048 + tid * 8);
        } else {
            const bool sec = kc >= ksplit;
            const int  kk  = sec ? kc - ksplit : kc;
            const int  lA  = sec ? lda2 : lda;
            const ushort* Asrc = (sec ? A2 : Ah) + Ab;
            gload16(&Asrc[ar0 * (long)lA + kk + soff], base + tid * 8);
            if constexpr (MREP == 4)
                gload16(&Asrc[ar1 * (long)lA + kk + soff], base + 2048 + tid * 8);
            ushort* bB = base + ATILE;
            const ushort* pB = Bh + Bz;
            gload16(&pB[br0 * ldb + kc + soff], bB + tid * 8);
            gload16(&pB[br1 * ldb + kc + soff], bB + 2048 + tid * 8);
        }
    };

    // ---- proven 2-buffer drain loop (K5) ----
    STAGE(0, 0);
    __syncthreads();
    for (int t = 0; t < NT; ++t) {
        const int cur = t & 1;
        const ushort* Acur = lds + cur * BUF;
        const ushort* Bcur = Acur + (SPLIT ? 2 * ATILE : ATILE);

        if (t + 1 < NT) STAGE(cur ^ 1, (t + 1) * 32);

        short8v a[MREP], b[4];
#pragma unroll
        for (int m = 0; m < MREP; ++m)
            a[m] = *(const short8v*)&Acur[(mw + m * 16 + fr) * 32 + rdsw];
#pragma unroll
        for (int n = 0; n < 4; ++n)
            b[n] = *(const short8v*)&Bcur[(nw + n * 16 + fr) * 32 + rdsw];

        if constexpr (SPLIT) {
            short8v al[MREP], bl[4];
#pragma unroll
            for (int m = 0; m < MREP; ++m)
                al[m] = *(const short8v*)&Acur[ATILE + (mw + m * 16 + fr) * 32 + rdsw];
#pragma unroll
            for (int n = 0; n < 4; ++n)
                bl[n] = *(const short8v*)&Bcur[BTILE + (nw + n * 16 + fr) * 32 + rdsw];
#pragma unroll
            for (int m = 0; m < MREP; ++m)
#pragma unroll
                for (int n = 0; n < 4; ++n) {
                    acc[m][n] = __builtin_amdgcn_mfma_f32_16x16x32_bf16(a[m],  b[n],  acc[m][n], 0, 0, 0);
                    acc[m][n] = __builtin_amdgcn_mfma_f32_16x16x32_bf16(a[m],  bl[n], acc[m][n], 0, 0, 0);
                    acc[m][n] = __builtin_amdgcn_mfma_f32_16x16x32_bf16(al[m], b[n],  acc[m][n], 0, 0, 0);
                }
        } else {
#pragma unroll
            for (int m = 0; m < MREP; ++m)
#pragma unroll
                for (int n = 0; n < 4; ++n)
                    acc[m][n] = __builtin_amdgcn_mfma_f32_16x16x32_bf16(a[m], b[n], acc[m][n], 0, 0, 0);
        }
        __syncthreads();
    }

    // ---- epilogue: D[r][c]: c = lane&15, r = (lane>>4)*4 + q
    const int fc = lane & 15;
    const int fq = (lane >> 4) * 4;

    float red[4][4];
#pragma unroll
    for (int m = 0; m < 4; ++m)
#pragma unroll
        for (int q = 0; q < 4; ++q) red[m][q] = 0.f;

    ushort* lo16 = (ushort*)aux;   // epi=3 low-half destination

#pragma unroll
    for (int n = 0; n < 4; ++n) {
        const int col = j0 + nw + n * 16 + fc;
        if (col >= Ncols) continue;
        const float bc = bias ? bias[col] : 0.f;
        const float wg = (epi == 2) ? Wg[col] : 0.f;
#pragma unroll
        for (int m = 0; m < MREP; ++m) {
            const int r0 = i0 + mw + m * 16 + fq;
            float4v v = acc[m][n];
#pragma unroll
            for (int q = 0; q < 4; ++q) {
                float x = v[q] + bc;
                const long ci = (long)bz * sC + (long)(r0 + q) * ldc + col;
                if (epi == 0) {
                    Cf[ci] = x;
                } else if (epi == 2) {
                    red[m][q] += tanhf(x) * wg;
                } else if (epi == 3) {
                    ushort h = f2bf(x);
                    C16[ci] = h;
                    lo16[ci] = f2bf(x - bf2f(h));
                } else {
                    C16[ci] = f2bf(x);
                }
            }
        }
    }
    if (epi == 2) {
#pragma unroll
        for (int m = 0; m < MREP; ++m)
#pragma unroll
            for (int q = 0; q < 4; ++q) {
                float s = red[m][q];
                s += __shfl_xor(s, 1);
                s += __shfl_xor(s, 2);
                s += __shfl_xor(s, 4);
                s += __shfl_xor(s, 8);
                if (fc == 0)
                    atomicAdd(&aux[i0 + mw + m * 16 + fq + q], s);
            }
    }
}

// ---------------------------------------------------------------------------
// Dedicated logits GEMM: 32x128 tile (MREP=1), K5 drain loop, direct epilogue.
// acc = 16 AGPR -> ~56 unified regs/wave -> 8 waves/SIMD; LDS 20 KB -> 8
// blocks/CU (160 KB). Occupancy axis is the only one that has responded
// (28->38->60% each bought time); this pushes it to ~85%+.
// A staged by threads 0..127 only (BM=32 rows x 4 slots); exec-masked.
// XCD swizzle: 32 M-tiles fast per XCD chunk (bijective; guard drops jt>=393).
// ---------------------------------------------------------------------------
__launch_bounds__(256, 8)
__global__ void gemm_logits(const ushort* __restrict__ A,
                            const ushort* __restrict__ B,
                            const float* __restrict__ bias,
                            float* __restrict__ C,
                            float* __restrict__ rowsum,
                            int Ncols, int K, int xcd_jtiles)
{
    constexpr int ATILE = 1024;             // 32x32 bf16 tile (2 KB)
    constexpr int BTILE = 4096;             // 128x32 bf16 tile (8 KB)
    constexpr int BUF   = ATILE + BTILE;
    __shared__ __align__(16) ushort lds[2 * BUF];   // 20 KB

    const int id = blockIdx.x;
    const int s = id >> 3;
    const int jt = (id & 7) * ((xcd_jtiles + 7) >> 3) + (s >> 5);
    const int mt = s & 31;
    if (jt >= xcd_jtiles) return;

    const int tid  = threadIdx.x;
    const int lane = tid & 63;
    const int wave = tid >> 6;
    const int mw = (wave >> 1) * 16, nw = (wave & 1) * 64;
    const int i0 = mt * 32, j0 = jt * 128;

    const int srow = tid >> 2;
    const int soff = ((tid & 3) ^ ((srow >> 1) & 3)) * 8;

    const long ar0 = i0 + (srow & 31);      // threads 0..127 cover rows 0..31
    long br0 = j0 + srow;      if (br0 > Ncols - 1) br0 = Ncols - 1;
    long br1 = j0 + 64 + srow; if (br1 > Ncols - 1) br1 = Ncols - 1;

    const int NT = K >> 5;
    const int fr = lane & 15;
    const int rdsw = ((lane >> 4) ^ ((fr >> 1) & 3)) * 8;

    float4v acc[4];
#pragma unroll
    for (int n = 0; n < 4; ++n) acc[n] = (float4v){0.f, 0.f, 0.f, 0.f};

    auto STAGE = [&](int buf, int kc) {
        ushort* base = lds + buf * BUF;
        if (tid < 128) gload16(&A[ar0 * K + kc + soff], base + tid * 8);
        ushort* bB = base + ATILE;
        gload16(&B[br0 * K + kc + soff], bB + tid * 8);
        gload16(&B[br1 * K + kc + soff], bB + 2048 + tid * 8);
    };

    STAGE(0, 0);
    __syncthreads();
    for (int t = 0; t < NT; ++t) {
        const int cur = t & 1;
        const ushort* Acur = lds + cur * BUF;
        const ushort* Bcur = Acur + ATILE;

        if (t + 1 < NT) STAGE(cur ^ 1, (t + 1) * 32);

        short8v a, b[4];
        a = *(const short8v*)&Acur[(mw + fr) * 32 + rdsw];
#pragma unroll
        for (int n = 0; n < 4; ++n)
            b[n] = *(const short8v*)&Bcur[(nw + n * 16 + fr) * 32 + rdsw];

#pragma unroll
        for (int n = 0; n < 4; ++n)
            acc[n] = __builtin_amdgcn_mfma_f32_16x16x32_bf16(a, b[n], acc[n], 0, 0, 0);
        __syncthreads();
    }

    // ---- direct epilogue: C store + bias + exp + 16-lane shfl rowsum reduce
    const int fc = lane & 15;
    const int fq = (lane >> 4) * 4;

    float red[4] = {0.f, 0.f, 0.f, 0.f};

#pragma unroll
    for (int n = 0; n < 4; ++n) {
        const int col = j0 + nw + n * 16 + fc;
        if (col >= Ncols) continue;
        const float bc = bias[col];
        const int r0 = i0 + mw + fq;
        float4v v = acc[n];
#pragma unroll
        for (int q = 0; q < 4; ++q) {
            float x = v[q] + bc;
            C[(long)(r0 + q) * Ncols + col] = x;
            red[q] += __expf(x);
        }
    }
#pragma unroll
    for (int q = 0; q < 4; ++q) {
        float sm = red[q];
        sm += __shfl_xor(sm, 1);
        sm += __shfl_xor(sm, 2);
        sm += __shfl_xor(sm, 4);
        sm += __shfl_xor(sm, 8);
        if (fc == 0)
            atomicAdd(&rowsum[i0 + mw + fq + q], sm);
    }
}

// ---- masked softmax over M=512, in place; also writes bf16 copy and zeroes
// ---- this row's rowsum/pgacc accumulators (runs before both GEMM consumers).
__global__ void softmax_rows(float* __restrict__ s, ushort* __restrict__ s16,
                             const int* __restrict__ msl,
                             float* __restrict__ rowsum, float* __restrict__ pgacc)
{
    __shared__ float red[256];
    const int row = blockIdx.x;
    const int b   = row / Tt;
    const int len = msl[b];
    float* p = s + (long)row * Mm;
    ushort* p16 = s16 + (long)row * Mm;
    const int tid = threadIdx.x;

    if (tid == 0) { rowsum[row] = 0.f; pgacc[row] = 0.f; }

    float v[2], mx = -INFINITY;
#pragma unroll
    for (int q = 0; q < 2; ++q) {
        int m = tid + q * 256;
        v[q] = (m < len) ? p[m] : -INFINITY;
        mx = fmaxf(mx, v[q]);
    }
    red[tid] = mx; __syncthreads();
    for (int off = 128; off > 0; off >>= 1) {
        if (tid < off) red[tid] = fmaxf(red[tid], red[tid + off]);
        __syncthreads();
    }
    mx = red[0]; __syncthreads();

    float e[2], sm = 0.f;
#pragma unroll
    for (int q = 0; q < 2; ++q) {
        int m = tid + q * 256;
        e[q] = (m < len) ? expf(v[q] - mx) : 0.f;
        sm += e[q];
    }
    red[tid] = sm; __syncthreads();
    for (int off = 128; off > 0; off >>= 1) {
        if (tid < off) red[tid] += red[tid + off];
        __syncthreads();
    }
    const float inv = 1.0f / red[0];
#pragma unroll
    for (int q = 0; q < 2; ++q) {
        float a = e[q] * inv;
        p[tid + q * 256] = a;
        p16[tid + q * 256] = f2bf(a);
    }
}

// ---- pure streaming shift: out[row][slice] += log(pg/rowsum) ----------------
static constexpr int QS = 8;
static constexpr int QW = DIV_UP(Vv, QS);   // 6283
__launch_bounds__(256)
__global__ void shift_rows(float* __restrict__ out, const float* __restrict__ pgacc,
                           const float* __restrict__ bg, const float* __restrict__ rowsum)
{
    const int row = blockIdx.y;
    const int qq  = blockIdx.x;
    const int tid = threadIdx.x;

    const int c0 = qq * QW;
    const int c1 = (c0 + QW < Vv) ? c0 + QW : Vv;
    const int cnt = c1 - c0;

    const float pgl = 1.0f / (1.0f + __expf(-(pgacc[row] + bg[0])));
    const float s = __logf(pgl / rowsum[row]);

    const long base = (long)row * Vv + c0;
    float* p = out + base;
    const int mis  = (int)(((unsigned)base) & 3u);
    int head = (4 - mis) & 3;
    if (head > cnt) head = cnt;
    if (tid < head) p[tid] += s;
    const int nv = (cnt - head) >> 2;
    float4* p4 = (float4*)(p + head);
    for (int i = tid; i < nv; i += 256) {
        float4 v = p4[i];
        v.x += s; v.y += s; v.z += s; v.w += s;
        p4[i] = v;
    }
    const int t = head + nv * 4 + tid;
    if (t < cnt) p[t] += s;
}

// ---- copy fix-up: LDS-hash dedupe (O(len)) + one scattered RMW per unique id.
__launch_bounds__(256)
__global__ void fixup_rows(float* __restrict__ out, const float* __restrict__ attn,
                           const float* __restrict__ pgacc, const float* __restrict__ bg,
                           const int* __restrict__ ids, const int* __restrict__ msl)
{
    __shared__ int   hkey[1024];
    __shared__ float hval[1024];
    const int row = blockIdx.x;
    const int b   = row / Tt;
    const int len = msl[b];
    const int tid = threadIdx.x;

    const float pgl = 1.0f / (1.0f + __expf(-(pgacc[row] + bg[0])));
    const float c = 1.0f - pgl;

    for (int i = tid; i < 1024; i += 256) { hkey[i] = -1; hval[i] = 0.f; }
    __syncthreads();

    for (int m = tid; m < len; m += 256) {
        const int id = ids[(long)b * Mm + m];
        const float v = attn[(long)row * Mm + m] * c;
        unsigned h = ((unsigned)id * 2654435761u) >> 22;   // 10-bit hash
        while (true) {
            int prev = atomicCAS(&hkey[h], -1, id);
            if (prev == -1 || prev == id) { atomicAdd(&hval[h], v); break; }
            h = (h + 1) & 1023u;
        }
    }
    __syncthreads();

    float* pr = out + (long)row * Vv;
    for (int i = tid; i < 1024; i += 256) {
        const int id = hkey[i];
        if (id >= 0) pr[id] = __logf(__expf(pr[id]) + hval[i]);
    }
}

extern "C" void kernel_launch(void* const* d_in, const int* in_sizes, int n_in,
                              void* d_out, int out_size, void* d_ws, size_t ws_size,
                              hipStream_t stream)
{
    const float* dec = (const float*)d_in[0];
    const float* mem = (const float*)d_in[1];
    const int*   msl = (const int*)d_in[2];
    const int*   ids = (const int*)d_in[3];
    const float* Wc  = (const float*)d_in[4];
    // d_in[5] = b_copy: per-(b,t)-constant shift of scores -> softmax-invariant; skip.
    const float* Wd  = (const float*)d_in[6];
    const float* bd  = (const float*)d_in[7];
    const float* Wg  = (const float*)d_in[8];
    const float* bg  = (const float*)d_in[9];
    const float* Wo  = (const float*)d_in[10];
    const float* bo  = (const float*)d_in[11];

    float* out = (float*)d_out;

    // ---- ws layout (~107 MB) ----
    float* ws     = (float*)d_ws;
    float* attn   = ws;                          // NN*Mm fp32 (survives to fixup)
    float* rowsum = attn + (size_t)NN * Mm;
    float* pgacc  = rowsum + NN;
    ushort* A16   = (ushort*)(pgacc + NN);       // dec_hi  NN*Dd
    ushort* B16   = A16 + (size_t)NN * Dd;       // W_out   Vv*Dd

    // ---- d_out doubles as scratch; everything consumed before logits GEMM ----
    ushort* S      = (ushort*)d_out;
    ushort* dec_lo = S;
    ushort* WcT_hi = dec_lo + (size_t)NN * Dd;
    ushort* WcT_lo = WcT_hi + (size_t)Dd * Dd;
    ushort* mem_hi = WcT_lo + (size_t)Dd * Dd;
    ushort* mem_lo = mem_hi + (size_t)Bb * Mm * Dd;
    ushort* memT16 = mem_lo + (size_t)Bb * Mm * Dd;
    ushort* dp_hi  = memT16 + (size_t)Bb * Mm * Dd;
    ushort* dp_lo  = dp_hi + (size_t)NN * Dd;
    ushort* Wd16   = dp_lo + (size_t)NN * Dd;
    ushort* attn16 = Wd16 + (size_t)Dd * 2 * Dd;
    ushort* ao16   = attn16 + (size_t)NN * Mm;   // attn_out bf16

    // 0. prep: all casts in one launch; transposes separate (LDS layout)
    prep_all<<<4096, 256, 0, stream>>>(dec, A16, dec_lo, mem, mem_hi, mem_lo,
                                       Wd, Wd16, Wo, B16);
    transpose_split<<<dim3(Dd/32, Dd/32, 1), 256, 0, stream>>>(Wc, WcT_hi, WcT_lo, Dd, Dd);
    transpose_split<<<dim3(Dd/32, Mm/32, Bb), 256, 0, stream>>>(mem, memT16, nullptr, Mm, Dd);

    // 1. dp = dec @ W_copy^T-form (split-bf16); epilogue writes hi/lo directly
    gemm_mx<true,2><<<dim3(Dd/128, NN/64, 1), 256, 0, stream>>>(
        A16, dec_lo, WcT_hi, WcT_lo, A16, Dd, Dd, nullptr,
        nullptr, dp_hi, (float*)dp_lo, nullptr,
        Dd, Dd, Dd, Dd, Dd, 0, 0, 0, 3);

    // 2. scores[b] = dp[b] @ mem[b]^T (split-bf16, batched)
    gemm_mx<true,2><<<dim3(Mm/128, Tt/64, Bb), 256, 0, stream>>>(
        dp_hi, dp_lo, mem_hi, mem_lo, dp_hi, Dd, Dd, nullptr,
        attn, nullptr, nullptr, nullptr,
        Mm, Dd, Dd, Dd, Mm, (long)Tt*Dd, (long)Mm*Dd, (long)Tt*Mm, 0);

    // 3. masked softmax (fp32 + bf16 outputs; zeroes rowsum/pgacc)
    softmax_rows<<<NN, 256, 0, stream>>>(attn, attn16, msl, rowsum, pgacc);

    // 4. attn_out16[b] = attn[b] @ mem[b] (bf16; feeds only p_gen)
    gemm_mx<false,2><<<dim3(Dd/128, Tt/64, Bb), 256, 0, stream>>>(
        attn16, attn16, memT16, memT16, attn16, Mm, Mm, nullptr,
        nullptr, ao16, nullptr, nullptr,
        Dd, Mm, Mm, Mm, Dd, (long)Tt*Mm, (long)Dd*Mm, (long)Tt*Dd, 4);

    // 5+6. pgacc[row] = sum_d tanh(([dec|attn_out] @ Wd^T + bd)[row,d]) * Wg[d]
    gemm_mx<false,2><<<dim3(Dd/128, NN/64, 1), 256, 0, stream>>>(
        A16, A16, Wd16, Wd16, ao16, Dd, Dd, bd,
        nullptr, nullptr, pgacc, Wg,
        Dd, 2*Dd, Dd, 2*Dd, 0, 0, 0, 0, 2);

    // 7. logits = dec @ W_out^T + b_out -> out; rowsum += sum(exp).
    //    32x128 tile, 8 waves/SIMD target, XCD swizzle (32 M-tiles fast).
    gemm_logits<<<8 * 32 * DIV_UP(DIV_UP(Vv,128), 8), 256, 0, stream>>>(
        A16, B16, bo, out, rowsum, Vv, Dd, DIV_UP(Vv,128));

    // 8. streaming shift (BW-bound, no scan; 8 slices/row)
    shift_rows<<<dim3(QS, NN), 256, 0, stream>>>(out, pgacc, bg, rowsum);

    // 9. copy fix-up: LDS-hash dedupe, one RMW per unique id
    fixup_rows<<<NN, 256, 0, stream>>>(out, attn, pgacc, bg, ids, msl);
}

// Round 22
// 499.559 us; speedup vs baseline: 1.1616x; 1.1616x over previous
//
#include <hip/hip_runtime.h>
#include <math.h>

#define DIV_UP(a,b) (((a)+(b)-1)/(b))

static constexpr int Bb = 4, Tt = 256, Mm = 512, Dd = 1024, Vv = 50257;
static constexpr int NN = Bb * Tt;   // 1024 flattened (b,t) rows

typedef __attribute__((ext_vector_type(8))) short short8v;
typedef __attribute__((ext_vector_type(4))) float float4v;
typedef unsigned short ushort;

// fp32 -> bf16 RNE (bit trick, branchless)
static __device__ __forceinline__ ushort f2bf(float f) {
    unsigned u = __float_as_uint(f);
    u += 0x7FFFu + ((u >> 16) & 1u);
    return (ushort)(u >> 16);
}
static __device__ __forceinline__ float bf2f(ushort h) {
    return __uint_as_float(((unsigned)h) << 16);
}

// async 16B global -> LDS (wave-uniform base + lane*16 dest)
static __device__ __forceinline__ void gload16(const void* g, void* l) {
    __builtin_amdgcn_global_load_lds(
        (const __attribute__((address_space(1))) unsigned int*)g,
        (__attribute__((address_space(3))) unsigned int*)l, 16, 0, 0);
}

// ---- fused prep: all input casts in ONE launch ------------------------------
static constexpr long PN0 = (long)NN * Dd / 8;
static constexpr long PN1 = (long)Bb * Mm * Dd / 8;
static constexpr long PN2 = (long)Dd * 2 * Dd / 8;
static constexpr long PN3 = (long)Vv * Dd / 8;
static constexpr long PTOT = PN0 + PN1 + PN2 + PN3;

__launch_bounds__(256)
__global__ void prep_all(const float* __restrict__ dec, ushort* __restrict__ A16,
                         ushort* __restrict__ dec_lo,
                         const float* __restrict__ mem, ushort* __restrict__ mem_hi,
                         ushort* __restrict__ mem_lo,
                         const float* __restrict__ Wd, ushort* __restrict__ Wd16,
                         const float* __restrict__ Wo, ushort* __restrict__ B16)
{
    for (long i = blockIdx.x * 256 + threadIdx.x; i < PTOT; i += (long)gridDim.x * 256) {
        const float* src; ushort* hi; ushort* lo = nullptr; long off;
        if (i < PN0)                  { src = dec; hi = A16;    lo = dec_lo; off = i; }
        else if (i < PN0 + PN1)       { src = mem; hi = mem_hi; lo = mem_lo; off = i - PN0; }
        else if (i < PN0 + PN1 + PN2) { src = Wd;  hi = Wd16;   off = i - PN0 - PN1; }
        else                          { src = Wo;  hi = B16;    off = i - PN0 - PN1 - PN2; }

        const float4 v0 = *(const float4*)&src[off * 8];
        const float4 v1 = *(const float4*)&src[off * 8 + 4];
        short8v th, tl;
        float vs[8] = {v0.x, v0.y, v0.z, v0.w, v1.x, v1.y, v1.z, v1.w};
#pragma unroll
        for (int q = 0; q < 8; ++q) {
            ushort h = f2bf(vs[q]);
            th[q] = h;
            tl[q] = f2bf(vs[q] - bf2f(h));
        }
        *(short8v*)&hi[off * 8] = th;
        if (lo) *(short8v*)&lo[off * 8] = tl;
    }
}

// ---- batched transpose: in[b] R x C fp32 -> out[b] C x R bf16 (hi, opt lo) --
__launch_bounds__(256)
__global__ void transpose_split(const float* __restrict__ in, ushort* __restrict__ oh,
                                ushort* __restrict__ ol, int R, int C)
{
    __shared__ float t[32][33];
    const int bz = blockIdx.z;
    in += (long)bz * R * C;
    oh += (long)bz * R * C;
    if (ol) ol += (long)bz * R * C;
    const int tx = threadIdx.x & 31, ty = threadIdx.x >> 5;
    const int r0 = blockIdx.y * 32, c0 = blockIdx.x * 32;
#pragma unroll
    for (int k = 0; k < 4; ++k)
        t[ty + k * 8][tx] = in[(long)(r0 + ty + k * 8) * C + c0 + tx];
    __syncthreads();
#pragma unroll
    for (int k = 0; k < 4; ++k) {
        float v = t[tx][ty + k * 8];
        ushort h = f2bf(v);
        long o = (long)(c0 + ty + k * 8) * R + r0 + tx;
        oh[o] = h;
        if (ol) ol[o] = f2bf(v - bf2f(h));
    }
}

// ---------------------------------------------------------------------------
// Unified bf16 MFMA GEMM (NT): C[i,j] = sum_k A[i,k]*B[j,k]
// Proven 2-buffer drain loop (K5 structure), BK=32, 4-slot XOR source swizzle.
// SPLIT: 3-pass split-bf16 (Ah*Bh + Ah*Bl + Al*Bh).
// MREP: wave M-fragments; block tile = (MREP*32) x 128.
// epi: 0 = fp32 C; 2 = pgacc[i] += sum tanh(x+b)*Wg; 3 = split hi/lo bf16 C;
//      4 = bf16 C write. (epi=1 lives in the dedicated gemm_logits kernel.)
// ---------------------------------------------------------------------------
template<bool SPLIT, int MREP>
__launch_bounds__(256)
__global__ void gemm_mx(const ushort* __restrict__ Ah, const ushort* __restrict__ Al,
                        const ushort* __restrict__ Bh, const ushort* __restrict__ Bl,
                        const ushort* __restrict__ A2, int ksplit, int lda2,
                        const float* __restrict__ bias,
                        float* __restrict__ Cf, ushort* __restrict__ C16,
                        float* __restrict__ aux, const float* __restrict__ Wg,
                        int Ncols, int K, int lda, int ldb, int ldc,
                        long sA, long sB, long sC, int epi)
{
    constexpr int BM    = MREP * 32;        // block rows
    constexpr int ATILE = BM * 32;          // ushorts per A tile (BM x 32)
    constexpr int BTILE = 4096;             // 128 x 32
    constexpr int BUF   = (SPLIT ? 2 : 1) * (ATILE + BTILE);
    __shared__ __align__(16) ushort lds[2 * BUF];

    const int jt = blockIdx.x, mt = blockIdx.y, bz = blockIdx.z;

    const int tid  = threadIdx.x;
    const int lane = tid & 63;
    const int wave = tid >> 6;
    const int mw = (wave >> 1) * (MREP * 16), nw = (wave & 1) * 64;
    const int i0 = mt * BM, j0 = jt * 128;

    const int srow = tid >> 2;                              // 0..63
    const int soff = ((tid & 3) ^ ((srow >> 1) & 3)) * 8;   // swizzled source slot

    const long Ab = (long)bz * sA;
    const long Bz = (long)bz * sB;
    const long ar0 = i0 + srow, ar1 = i0 + 64 + srow;       // ar1 used iff MREP==4
    long br0 = j0 + srow;      if (br0 > Ncols - 1) br0 = Ncols - 1;
    long br1 = j0 + 64 + srow; if (br1 > Ncols - 1) br1 = Ncols - 1;

    const int NT = K >> 5;
    const int fr = lane & 15;
    const int rdsw = ((lane >> 4) ^ ((fr >> 1) & 3)) * 8;   // swizzled read slot

    float4v acc[MREP][4];
#pragma unroll
    for (int m = 0; m < MREP; ++m)
#pragma unroll
        for (int n = 0; n < 4; ++n) acc[m][n] = (float4v){0.f, 0.f, 0.f, 0.f};

    auto STAGE = [&](int buf, int kc) {
        ushort* base = lds + buf * BUF;
        if constexpr (SPLIT) {
            const ushort* pAh = Ah + Ab; const ushort* pAl = Al + Ab;
            const ushort* pBh = Bh + Bz; const ushort* pBl = Bl + Bz;
            gload16(&pAh[ar0 * lda + kc + soff], base + tid * 8);
            if constexpr (MREP == 4)
                gload16(&pAh[ar1 * lda + kc + soff], base + 2048 + tid * 8);
            ushort* bAl = base + ATILE;
            gload16(&pAl[ar0 * lda + kc + soff], bAl + tid * 8);
            if constexpr (MREP == 4)
                gload16(&pAl[ar1 * lda + kc + soff], bAl + 2048 + tid * 8);
            ushort* bBh = base + 2 * ATILE;
            gload16(&pBh[br0 * ldb + kc + soff], bBh + tid * 8);
            gload16(&pBh[br1 * ldb + kc + soff], bBh + 2048 + tid * 8);
            ushort* bBl = bBh + BTILE;
            gload16(&pBl[br0 * ldb + kc + soff], bBl + tid * 8);
            gload16(&pBl[br1 * ldb + kc + soff], bBl + 2048 + tid * 8);
        } else {
            const bool sec = kc >= ksplit;
            const int  kk  = sec ? kc - ksplit : kc;
            const int  lA  = sec ? lda2 : lda;
            const ushort* Asrc = (sec ? A2 : Ah) + Ab;
            gload16(&Asrc[ar0 * (long)lA + kk + soff], base + tid * 8);
            if constexpr (MREP == 4)
                gload16(&Asrc[ar1 * (long)lA + kk + soff], base + 2048 + tid * 8);
            ushort* bB = base + ATILE;
            const ushort* pB = Bh + Bz;
            gload16(&pB[br0 * ldb + kc + soff], bB + tid * 8);
            gload16(&pB[br1 * ldb + kc + soff], bB + 2048 + tid * 8);
        }
    };

    // ---- proven 2-buffer drain loop (K5) ----
    STAGE(0, 0);
    __syncthreads();
    for (int t = 0; t < NT; ++t) {
        const int cur = t & 1;
        const ushort* Acur = lds + cur * BUF;
        const ushort* Bcur = Acur + (SPLIT ? 2 * ATILE : ATILE);

        if (t + 1 < NT) STAGE(cur ^ 1, (t + 1) * 32);

        short8v a[MREP], b[4];
#pragma unroll
        for (int m = 0; m < MREP; ++m)
            a[m] = *(const short8v*)&Acur[(mw + m * 16 + fr) * 32 + rdsw];
#pragma unroll
        for (int n = 0; n < 4; ++n)
            b[n] = *(const short8v*)&Bcur[(nw + n * 16 + fr) * 32 + rdsw];

        if constexpr (SPLIT) {
            short8v al[MREP], bl[4];
#pragma unroll
            for (int m = 0; m < MREP; ++m)
                al[m] = *(const short8v*)&Acur[ATILE + (mw + m * 16 + fr) * 32 + rdsw];
#pragma unroll
            for (int n = 0; n < 4; ++n)
                bl[n] = *(const short8v*)&Bcur[BTILE + (nw + n * 16 + fr) * 32 + rdsw];
#pragma unroll
            for (int m = 0; m < MREP; ++m)
#pragma unroll
                for (int n = 0; n < 4; ++n) {
                    acc[m][n] = __builtin_amdgcn_mfma_f32_16x16x32_bf16(a[m],  b[n],  acc[m][n], 0, 0, 0);
                    acc[m][n] = __builtin_amdgcn_mfma_f32_16x16x32_bf16(a[m],  bl[n], acc[m][n], 0, 0, 0);
                    acc[m][n] = __builtin_amdgcn_mfma_f32_16x16x32_bf16(al[m], b[n],  acc[m][n], 0, 0, 0);
                }
        } else {
#pragma unroll
            for (int m = 0; m < MREP; ++m)
#pragma unroll
                for (int n = 0; n < 4; ++n)
                    acc[m][n] = __builtin_amdgcn_mfma_f32_16x16x32_bf16(a[m], b[n], acc[m][n], 0, 0, 0);
        }
        __syncthreads();
    }

    // ---- epilogue: D[r][c]: c = lane&15, r = (lane>>4)*4 + q
    const int fc = lane & 15;
    const int fq = (lane >> 4) * 4;

    float red[4][4];
#pragma unroll
    for (int m = 0; m < 4; ++m)
#pragma unroll
        for (int q = 0; q < 4; ++q) red[m][q] = 0.f;

    ushort* lo16 = (ushort*)aux;   // epi=3 low-half destination

#pragma unroll
    for (int n = 0; n < 4; ++n) {
        const int col = j0 + nw + n * 16 + fc;
        if (col >= Ncols) continue;
        const float bc = bias ? bias[col] : 0.f;
        const float wg = (epi == 2) ? Wg[col] : 0.f;
#pragma unroll
        for (int m = 0; m < MREP; ++m) {
            const int r0 = i0 + mw + m * 16 + fq;
            float4v v = acc[m][n];
#pragma unroll
            for (int q = 0; q < 4; ++q) {
                float x = v[q] + bc;
                const long ci = (long)bz * sC + (long)(r0 + q) * ldc + col;
                if (epi == 0) {
                    Cf[ci] = x;
                } else if (epi == 2) {
                    red[m][q] += tanhf(x) * wg;
                } else if (epi == 3) {
                    ushort h = f2bf(x);
                    C16[ci] = h;
                    lo16[ci] = f2bf(x - bf2f(h));
                } else {
                    C16[ci] = f2bf(x);
                }
            }
        }
    }
    if (epi == 2) {
#pragma unroll
        for (int m = 0; m < MREP; ++m)
#pragma unroll
            for (int q = 0; q < 4; ++q) {
                float s = red[m][q];
                s += __shfl_xor(s, 1);
                s += __shfl_xor(s, 2);
                s += __shfl_xor(s, 4);
                s += __shfl_xor(s, 8);
                if (fc == 0)
                    atomicAdd(&aux[i0 + mw + m * 16 + fq + q], s);
            }
    }
}

// ---------------------------------------------------------------------------
// Dedicated logits GEMM: 64x128 tile (MREP=2), K5 drain loop, direct epilogue.
// Measured optimum of the tile-M family: 128x128@38% occ = 248 us;
// 64x128@60% occ = 234 us; 32x128@85% occ = 328 us. Interior optimum.
// XCD swizzle: 16 M-tiles fast per XCD chunk (bijective; guard drops jt>=393).
// ---------------------------------------------------------------------------
__launch_bounds__(256, 5)
__global__ void gemm_logits(const ushort* __restrict__ A,
                            const ushort* __restrict__ B,
                            const float* __restrict__ bias,
                            float* __restrict__ C,
                            float* __restrict__ rowsum,
                            int Ncols, int K, int xcd_jtiles)
{
    constexpr int ATILE = 2048;             // 64x32 bf16 tile
    constexpr int BTILE = 4096;             // 128x32 bf16 tile
    constexpr int BUF   = ATILE + BTILE;
    __shared__ __align__(16) ushort lds[2 * BUF];   // 24 KB

    const int id = blockIdx.x;
    const int s = id >> 3;
    const int jt = (id & 7) * ((xcd_jtiles + 7) >> 3) + (s >> 4);
    const int mt = s & 15;
    if (jt >= xcd_jtiles) return;

    const int tid  = threadIdx.x;
    const int lane = tid & 63;
    const int wave = tid >> 6;
    const int mw = (wave >> 1) * 32, nw = (wave & 1) * 64;
    const int i0 = mt * 64, j0 = jt * 128;

    const int srow = tid >> 2;
    const int soff = ((tid & 3) ^ ((srow >> 1) & 3)) * 8;

    const long ar0 = i0 + srow;
    long br0 = j0 + srow;      if (br0 > Ncols - 1) br0 = Ncols - 1;
    long br1 = j0 + 64 + srow; if (br1 > Ncols - 1) br1 = Ncols - 1;

    const int NT = K >> 5;
    const int fr = lane & 15;
    const int rdsw = ((lane >> 4) ^ ((fr >> 1) & 3)) * 8;

    float4v acc[2][4];
#pragma unroll
    for (int m = 0; m < 2; ++m)
#pragma unroll
        for (int n = 0; n < 4; ++n) acc[m][n] = (float4v){0.f, 0.f, 0.f, 0.f};

    auto STAGE = [&](int buf, int kc) {
        ushort* base = lds + buf * BUF;
        gload16(&A[ar0 * K + kc + soff], base + tid * 8);
        ushort* bB = base + ATILE;
        gload16(&B[br0 * K + kc + soff], bB + tid * 8);
        gload16(&B[br1 * K + kc + soff], bB + 2048 + tid * 8);
    };

    STAGE(0, 0);
    __syncthreads();
    for (int t = 0; t < NT; ++t) {
        const int cur = t & 1;
        const ushort* Acur = lds + cur * BUF;
        const ushort* Bcur = Acur + ATILE;

        if (t + 1 < NT) STAGE(cur ^ 1, (t + 1) * 32);

        short8v a[2], b[4];
#pragma unroll
        for (int m = 0; m < 2; ++m)
            a[m] = *(const short8v*)&Acur[(mw + m * 16 + fr) * 32 + rdsw];
#pragma unroll
        for (int n = 0; n < 4; ++n)
            b[n] = *(const short8v*)&Bcur[(nw + n * 16 + fr) * 32 + rdsw];

#pragma unroll
        for (int m = 0; m < 2; ++m)
#pragma unroll
            for (int n = 0; n < 4; ++n)
                acc[m][n] = __builtin_amdgcn_mfma_f32_16x16x32_bf16(a[m], b[n], acc[m][n], 0, 0, 0);
        __syncthreads();
    }

    // ---- direct epilogue: C store + bias + exp + 16-lane shfl rowsum reduce
    const int fc = lane & 15;
    const int fq = (lane >> 4) * 4;

    float red[2][4];
#pragma unroll
    for (int m = 0; m < 2; ++m)
#pragma unroll
        for (int q = 0; q < 4; ++q) red[m][q] = 0.f;

#pragma unroll
    for (int n = 0; n < 4; ++n) {
        const int col = j0 + nw + n * 16 + fc;
        if (col >= Ncols) continue;
        const float bc = bias[col];
#pragma unroll
        for (int m = 0; m < 2; ++m) {
            const int r0 = i0 + mw + m * 16 + fq;
            float4v v = acc[m][n];
#pragma unroll
            for (int q = 0; q < 4; ++q) {
                float x = v[q] + bc;
                C[(long)(r0 + q) * Ncols + col] = x;
                red[m][q] += __expf(x);
            }
        }
    }
#pragma unroll
    for (int m = 0; m < 2; ++m)
#pragma unroll
        for (int q = 0; q < 4; ++q) {
            float sm = red[m][q];
            sm += __shfl_xor(sm, 1);
            sm += __shfl_xor(sm, 2);
            sm += __shfl_xor(sm, 4);
            sm += __shfl_xor(sm, 8);
            if (fc == 0)
                atomicAdd(&rowsum[i0 + mw + m * 16 + fq + q], sm);
        }
}

// ---- masked softmax over M=512, in place; also writes bf16 copy and zeroes
// ---- this row's rowsum/pgacc accumulators (runs before both GEMM consumers).
__global__ void softmax_rows(float* __restrict__ s, ushort* __restrict__ s16,
                             const int* __restrict__ msl,
                             float* __restrict__ rowsum, float* __restrict__ pgacc)
{
    __shared__ float red[256];
    const int row = blockIdx.x;
    const int b   = row / Tt;
    const int len = msl[b];
    float* p = s + (long)row * Mm;
    ushort* p16 = s16 + (long)row * Mm;
    const int tid = threadIdx.x;

    if (tid == 0) { rowsum[row] = 0.f; pgacc[row] = 0.f; }

    float v[2], mx = -INFINITY;
#pragma unroll
    for (int q = 0; q < 2; ++q) {
        int m = tid + q * 256;
        v[q] = (m < len) ? p[m] : -INFINITY;
        mx = fmaxf(mx, v[q]);
    }
    red[tid] = mx; __syncthreads();
    for (int off = 128; off > 0; off >>= 1) {
        if (tid < off) red[tid] = fmaxf(red[tid], red[tid + off]);
        __syncthreads();
    }
    mx = red[0]; __syncthreads();

    float e[2], sm = 0.f;
#pragma unroll
    for (int q = 0; q < 2; ++q) {
        int m = tid + q * 256;
        e[q] = (m < len) ? expf(v[q] - mx) : 0.f;
        sm += e[q];
    }
    red[tid] = sm; __syncthreads();
    for (int off = 128; off > 0; off >>= 1) {
        if (tid < off) red[tid] += red[tid + off];
        __syncthreads();
    }
    const float inv = 1.0f / red[0];
#pragma unroll
    for (int q = 0; q < 2; ++q) {
        float a = e[q] * inv;
        p[tid + q * 256] = a;
        p16[tid + q * 256] = f2bf(a);
    }
}

// ---- pure streaming shift: out[row][slice] += log(pg/rowsum) ----------------
static constexpr int QS = 8;
static constexpr int QW = DIV_UP(Vv, QS);   // 6283
__launch_bounds__(256)
__global__ void shift_rows(float* __restrict__ out, const float* __restrict__ pgacc,
                           const float* __restrict__ bg, const float* __restrict__ rowsum)
{
    const int row = blockIdx.y;
    const int qq  = blockIdx.x;
    const int tid = threadIdx.x;

    const int c0 = qq * QW;
    const int c1 = (c0 + QW < Vv) ? c0 + QW : Vv;
    const int cnt = c1 - c0;

    const float pgl = 1.0f / (1.0f + __expf(-(pgacc[row] + bg[0])));
    const float s = __logf(pgl / rowsum[row]);

    const long base = (long)row * Vv + c0;
    float* p = out + base;
    const int mis  = (int)(((unsigned)base) & 3u);
    int head = (4 - mis) & 3;
    if (head > cnt) head = cnt;
    if (tid < head) p[tid] += s;
    const int nv = (cnt - head) >> 2;
    float4* p4 = (float4*)(p + head);
    for (int i = tid; i < nv; i += 256) {
        float4 v = p4[i];
        v.x += s; v.y += s; v.z += s; v.w += s;
        p4[i] = v;
    }
    const int t = head + nv * 4 + tid;
    if (t < cnt) p[t] += s;
}

// ---- copy fix-up: LDS-hash dedupe (O(len)) + one scattered RMW per unique id.
__launch_bounds__(256)
__global__ void fixup_rows(float* __restrict__ out, const float* __restrict__ attn,
                           const float* __restrict__ pgacc, const float* __restrict__ bg,
                           const int* __restrict__ ids, const int* __restrict__ msl)
{
    __shared__ int   hkey[1024];
    __shared__ float hval[1024];
    const int row = blockIdx.x;
    const int b   = row / Tt;
    const int len = msl[b];
    const int tid = threadIdx.x;

    const float pgl = 1.0f / (1.0f + __expf(-(pgacc[row] + bg[0])));
    const float c = 1.0f - pgl;

    for (int i = tid; i < 1024; i += 256) { hkey[i] = -1; hval[i] = 0.f; }
    __syncthreads();

    for (int m = tid; m < len; m += 256) {
        const int id = ids[(long)b * Mm + m];
        const float v = attn[(long)row * Mm + m] * c;
        unsigned h = ((unsigned)id * 2654435761u) >> 22;   // 10-bit hash
        while (true) {
            int prev = atomicCAS(&hkey[h], -1, id);
            if (prev == -1 || prev == id) { atomicAdd(&hval[h], v); break; }
            h = (h + 1) & 1023u;
        }
    }
    __syncthreads();

    float* pr = out + (long)row * Vv;
    for (int i = tid; i < 1024; i += 256) {
        const int id = hkey[i];
        if (id >= 0) pr[id] = __logf(__expf(pr[id]) + hval[i]);
    }
}

extern "C" void kernel_launch(void* const* d_in, const int* in_sizes, int n_in,
                              void* d_out, int out_size, void* d_ws, size_t ws_size,
                              hipStream_t stream)
{
    const float* dec = (const float*)d_in[0];
    const float* mem = (const float*)d_in[1];
    const int*   msl = (const int*)d_in[2];
    const int*   ids = (const int*)d_in[3];
    const float* Wc  = (const float*)d_in[4];
    // d_in[5] = b_copy: per-(b,t)-constant shift of scores -> softmax-invariant; skip.
    const float* Wd  = (const float*)d_in[6];
    const float* bd  = (const float*)d_in[7];
    const float* Wg  = (const float*)d_in[8];
    const float* bg  = (const float*)d_in[9];
    const float* Wo  = (const float*)d_in[10];
    const float* bo  = (const float*)d_in[11];

    float* out = (float*)d_out;

    // ---- ws layout (~107 MB) ----
    float* ws     = (float*)d_ws;
    float* attn   = ws;                          // NN*Mm fp32 (survives to fixup)
    float* rowsum = attn + (size_t)NN * Mm;
    float* pgacc  = rowsum + NN;
    ushort* A16   = (ushort*)(pgacc + NN);       // dec_hi  NN*Dd
    ushort* B16   = A16 + (size_t)NN * Dd;       // W_out   Vv*Dd

    // ---- d_out doubles as scratch; everything consumed before logits GEMM ----
    ushort* S      = (ushort*)d_out;
    ushort* dec_lo = S;
    ushort* WcT_hi = dec_lo + (size_t)NN * Dd;
    ushort* WcT_lo = WcT_hi + (size_t)Dd * Dd;
    ushort* mem_hi = WcT_lo + (size_t)Dd * Dd;
    ushort* mem_lo = mem_hi + (size_t)Bb * Mm * Dd;
    ushort* memT16 = mem_lo + (size_t)Bb * Mm * Dd;
    ushort* dp_hi  = memT16 + (size_t)Bb * Mm * Dd;
    ushort* dp_lo  = dp_hi + (size_t)NN * Dd;
    ushort* Wd16   = dp_lo + (size_t)NN * Dd;
    ushort* attn16 = Wd16 + (size_t)Dd * 2 * Dd;
    ushort* ao16   = attn16 + (size_t)NN * Mm;   // attn_out bf16

    // 0. prep: all casts in one launch; transposes separate (LDS layout)
    prep_all<<<4096, 256, 0, stream>>>(dec, A16, dec_lo, mem, mem_hi, mem_lo,
                                       Wd, Wd16, Wo, B16);
    transpose_split<<<dim3(Dd/32, Dd/32, 1), 256, 0, stream>>>(Wc, WcT_hi, WcT_lo, Dd, Dd);
    transpose_split<<<dim3(Dd/32, Mm/32, Bb), 256, 0, stream>>>(mem, memT16, nullptr, Mm, Dd);

    // 1. dp = dec @ W_copy^T-form (split-bf16); epilogue writes hi/lo directly
    gemm_mx<true,2><<<dim3(Dd/128, NN/64, 1), 256, 0, stream>>>(
        A16, dec_lo, WcT_hi, WcT_lo, A16, Dd, Dd, nullptr,
        nullptr, dp_hi, (float*)dp_lo, nullptr,
        Dd, Dd, Dd, Dd, Dd, 0, 0, 0, 3);

    // 2. scores[b] = dp[b] @ mem[b]^T (split-bf16, batched)
    gemm_mx<true,2><<<dim3(Mm/128, Tt/64, Bb), 256, 0, stream>>>(
        dp_hi, dp_lo, mem_hi, mem_lo, dp_hi, Dd, Dd, nullptr,
        attn, nullptr, nullptr, nullptr,
        Mm, Dd, Dd, Dd, Mm, (long)Tt*Dd, (long)Mm*Dd, (long)Tt*Mm, 0);

    // 3. masked softmax (fp32 + bf16 outputs; zeroes rowsum/pgacc)
    softmax_rows<<<NN, 256, 0, stream>>>(attn, attn16, msl, rowsum, pgacc);

    // 4. attn_out16[b] = attn[b] @ mem[b] (bf16; feeds only p_gen)
    gemm_mx<false,2><<<dim3(Dd/128, Tt/64, Bb), 256, 0, stream>>>(
        attn16, attn16, memT16, memT16, attn16, Mm, Mm, nullptr,
        nullptr, ao16, nullptr, nullptr,
        Dd, Mm, Mm, Mm, Dd, (long)Tt*Mm, (long)Dd*Mm, (long)Tt*Dd, 4);

    // 5+6. pgacc[row] = sum_d tanh(([dec|attn_out] @ Wd^T + bd)[row,d]) * Wg[d]
    gemm_mx<false,2><<<dim3(Dd/128, NN/64, 1), 256, 0, stream>>>(
        A16, A16, Wd16, Wd16, ao16, Dd, Dd, bd,
        nullptr, nullptr, pgacc, Wg,
        Dd, 2*Dd, Dd, 2*Dd, 0, 0, 0, 0, 2);

    // 7. logits = dec @ W_out^T + b_out -> out; rowsum += sum(exp).
    //    64x128 tile (measured optimum), 5 waves/SIMD, XCD swizzle.
    gemm_logits<<<8 * 16 * DIV_UP(DIV_UP(Vv,128), 8), 256, 0, stream>>>(
        A16, B16, bo, out, rowsum, Vv, Dd, DIV_UP(Vv,128));

    // 8. streaming shift (BW-bound, no scan; 8 slices/row)
    shift_rows<<<dim3(QS, NN), 256, 0, stream>>>(out, pgacc, bg, rowsum);

    // 9. copy fix-up: LDS-hash dedupe, one RMW per unique id
    fixup_rows<<<NN, 256, 0, stream>>>(out, attn, pgacc, bg, ids, msl);
}

// Round 23
// 497.058 us; speedup vs baseline: 1.1674x; 1.0050x over previous
//
#include <hip/hip_runtime.h>
#include <math.h>

#define DIV_UP(a,b) (((a)+(b)-1)/(b))

static constexpr int Bb = 4, Tt = 256, Mm = 512, Dd = 1024, Vv = 50257;
static constexpr int NN = Bb * Tt;   // 1024 flattened (b,t) rows

typedef __attribute__((ext_vector_type(8))) short short8v;
typedef __attribute__((ext_vector_type(4))) float float4v;
typedef unsigned short ushort;

// fp32 -> bf16 RNE (bit trick, branchless)
static __device__ __forceinline__ ushort f2bf(float f) {
    unsigned u = __float_as_uint(f);
    u += 0x7FFFu + ((u >> 16) & 1u);
    return (ushort)(u >> 16);
}
static __device__ __forceinline__ float bf2f(ushort h) {
    return __uint_as_float(((unsigned)h) << 16);
}

// async 16B global -> LDS (wave-uniform base + lane*16 dest)
static __device__ __forceinline__ void gload16(const void* g, void* l) {
    __builtin_amdgcn_global_load_lds(
        (const __attribute__((address_space(1))) unsigned int*)g,
        (__attribute__((address_space(3))) unsigned int*)l, 16, 0, 0);
}

// ---- fused prep: all input casts in ONE launch ------------------------------
static constexpr long PN0 = (long)NN * Dd / 8;
static constexpr long PN1 = (long)Bb * Mm * Dd / 8;
static constexpr long PN2 = (long)Dd * 2 * Dd / 8;
static constexpr long PN3 = (long)Vv * Dd / 8;
static constexpr long PTOT = PN0 + PN1 + PN2 + PN3;

__launch_bounds__(256)
__global__ void prep_all(const float* __restrict__ dec, ushort* __restrict__ A16,
                         ushort* __restrict__ dec_lo,
                         const float* __restrict__ mem, ushort* __restrict__ mem_hi,
                         ushort* __restrict__ mem_lo,
                         const float* __restrict__ Wd, ushort* __restrict__ Wd16,
                         const float* __restrict__ Wo, ushort* __restrict__ B16)
{
    for (long i = blockIdx.x * 256 + threadIdx.x; i < PTOT; i += (long)gridDim.x * 256) {
        const float* src; ushort* hi; ushort* lo = nullptr; long off;
        if (i < PN0)                  { src = dec; hi = A16;    lo = dec_lo; off = i; }
        else if (i < PN0 + PN1)       { src = mem; hi = mem_hi; lo = mem_lo; off = i - PN0; }
        else if (i < PN0 + PN1 + PN2) { src = Wd;  hi = Wd16;   off = i - PN0 - PN1; }
        else                          { src = Wo;  hi = B16;    off = i - PN0 - PN1 - PN2; }

        const float4 v0 = *(const float4*)&src[off * 8];
        const float4 v1 = *(const float4*)&src[off * 8 + 4];
        short8v th, tl;
        float vs[8] = {v0.x, v0.y, v0.z, v0.w, v1.x, v1.y, v1.z, v1.w};
#pragma unroll
        for (int q = 0; q < 8; ++q) {
            ushort h = f2bf(vs[q]);
            th[q] = h;
            tl[q] = f2bf(vs[q] - bf2f(h));
        }
        *(short8v*)&hi[off * 8] = th;
        if (lo) *(short8v*)&lo[off * 8] = tl;
    }
}

// ---- batched transpose: in[b] R x C fp32 -> out[b] C x R bf16 (hi, opt lo) --
__launch_bounds__(256)
__global__ void transpose_split(const float* __restrict__ in, ushort* __restrict__ oh,
                                ushort* __restrict__ ol, int R, int C)
{
    __shared__ float t[32][33];
    const int bz = blockIdx.z;
    in += (long)bz * R * C;
    oh += (long)bz * R * C;
    if (ol) ol += (long)bz * R * C;
    const int tx = threadIdx.x & 31, ty = threadIdx.x >> 5;
    const int r0 = blockIdx.y * 32, c0 = blockIdx.x * 32;
#pragma unroll
    for (int k = 0; k < 4; ++k)
        t[ty + k * 8][tx] = in[(long)(r0 + ty + k * 8) * C + c0 + tx];
    __syncthreads();
#pragma unroll
    for (int k = 0; k < 4; ++k) {
        float v = t[tx][ty + k * 8];
        ushort h = f2bf(v);
        long o = (long)(c0 + ty + k * 8) * R + r0 + tx;
        oh[o] = h;
        if (ol) ol[o] = f2bf(v - bf2f(h));
    }
}

// ---------------------------------------------------------------------------
// Unified bf16 MFMA GEMM (NT): C[i,j] = sum_k A[i,k]*B[j,k]
// Proven 2-buffer drain loop (K5 structure), BK=32, 4-slot XOR source swizzle.
// SPLIT: 3-pass split-bf16 (Ah*Bh + Ah*Bl + Al*Bh).
// MREP: wave M-fragments; block tile = (MREP*32) x 128.
// epi: 0 = fp32 C; 2 = pgacc[i] += sum tanh(x+b)*Wg; 3 = split hi/lo bf16 C;
//      4 = bf16 C write. (epi=1 lives in the dedicated gemm_logits kernel.)
// ---------------------------------------------------------------------------
template<bool SPLIT, int MREP>
__launch_bounds__(256)
__global__ void gemm_mx(const ushort* __restrict__ Ah, const ushort* __restrict__ Al,
                        const ushort* __restrict__ Bh, const ushort* __restrict__ Bl,
                        const ushort* __restrict__ A2, int ksplit, int lda2,
                        const float* __restrict__ bias,
                        float* __restrict__ Cf, ushort* __restrict__ C16,
                        float* __restrict__ aux, const float* __restrict__ Wg,
                        int Ncols, int K, int lda, int ldb, int ldc,
                        long sA, long sB, long sC, int epi)
{
    constexpr int BM    = MREP * 32;        // block rows
    constexpr int ATILE = BM * 32;          // ushorts per A tile (BM x 32)
    constexpr int BTILE = 4096;             // 128 x 32
    constexpr int BUF   = (SPLIT ? 2 : 1) * (ATILE + BTILE);
    __shared__ __align__(16) ushort lds[2 * BUF];

    const int jt = blockIdx.x, mt = blockIdx.y, bz = blockIdx.z;

    const int tid  = threadIdx.x;
    const int lane = tid & 63;
    const int wave = tid >> 6;
    const int mw = (wave >> 1) * (MREP * 16), nw = (wave & 1) * 64;
    const int i0 = mt * BM, j0 = jt * 128;

    const int srow = tid >> 2;                              // 0..63
    const int soff = ((tid & 3) ^ ((srow >> 1) & 3)) * 8;   // swizzled source slot

    const long Ab = (long)bz * sA;
    const long Bz = (long)bz * sB;
    const long ar0 = i0 + srow, ar1 = i0 + 64 + srow;       // ar1 used iff MREP==4
    long br0 = j0 + srow;      if (br0 > Ncols - 1) br0 = Ncols - 1;
    long br1 = j0 + 64 + srow; if (br1 > Ncols - 1) br1 = Ncols - 1;

    const int NT = K >> 5;
    const int fr = lane & 15;
    const int rdsw = ((lane >> 4) ^ ((fr >> 1) & 3)) * 8;   // swizzled read slot

    float4v acc[MREP][4];
#pragma unroll
    for (int m = 0; m < MREP; ++m)
#pragma unroll
        for (int n = 0; n < 4; ++n) acc[m][n] = (float4v){0.f, 0.f, 0.f, 0.f};

    auto STAGE = [&](int buf, int kc) {
        ushort* base = lds + buf * BUF;
        if constexpr (SPLIT) {
            const ushort* pAh = Ah + Ab; const ushort* pAl = Al + Ab;
            const ushort* pBh = Bh + Bz; const ushort* pBl = Bl + Bz;
            gload16(&pAh[ar0 * lda + kc + soff], base + tid * 8);
            if constexpr (MREP == 4)
                gload16(&pAh[ar1 * lda + kc + soff], base + 2048 + tid * 8);
            ushort* bAl = base + ATILE;
            gload16(&pAl[ar0 * lda + kc + soff], bAl + tid * 8);
            if constexpr (MREP == 4)
                gload16(&pAl[ar1 * lda + kc + soff], bAl + 2048 + tid * 8);
            ushort* bBh = base + 2 * ATILE;
            gload16(&pBh[br0 * ldb + kc + soff], bBh + tid * 8);
            gload16(&pBh[br1 * ldb + kc + soff], bBh + 2048 + tid * 8);
            ushort* bBl = bBh + BTILE;
            gload16(&pBl[br0 * ldb + kc + soff], bBl + tid * 8);
            gload16(&pBl[br1 * ldb + kc + soff], bBl + 2048 + tid * 8);
        } else {
            const bool sec = kc >= ksplit;
            const int  kk  = sec ? kc - ksplit : kc;
            const int  lA  = sec ? lda2 : lda;
            const ushort* Asrc = (sec ? A2 : Ah) + Ab;
            gload16(&Asrc[ar0 * (long)lA + kk + soff], base + tid * 8);
            if constexpr (MREP == 4)
                gload16(&Asrc[ar1 * (long)lA + kk + soff], base + 2048 + tid * 8);
            ushort* bB = base + ATILE;
            const ushort* pB = Bh + Bz;
            gload16(&pB[br0 * ldb + kc + soff], bB + tid * 8);
            gload16(&pB[br1 * ldb + kc + soff], bB + 2048 + tid * 8);
        }
    };

    // ---- proven 2-buffer drain loop (K5) ----
    STAGE(0, 0);
    __syncthreads();
    for (int t = 0; t < NT; ++t) {
        const int cur = t & 1;
        const ushort* Acur = lds + cur * BUF;
        const ushort* Bcur = Acur + (SPLIT ? 2 * ATILE : ATILE);

        if (t + 1 < NT) STAGE(cur ^ 1, (t + 1) * 32);

        short8v a[MREP], b[4];
#pragma unroll
        for (int m = 0; m < MREP; ++m)
            a[m] = *(const short8v*)&Acur[(mw + m * 16 + fr) * 32 + rdsw];
#pragma unroll
        for (int n = 0; n < 4; ++n)
            b[n] = *(const short8v*)&Bcur[(nw + n * 16 + fr) * 32 + rdsw];

        if constexpr (SPLIT) {
            short8v al[MREP], bl[4];
#pragma unroll
            for (int m = 0; m < MREP; ++m)
                al[m] = *(const short8v*)&Acur[ATILE + (mw + m * 16 + fr) * 32 + rdsw];
#pragma unroll
            for (int n = 0; n < 4; ++n)
                bl[n] = *(const short8v*)&Bcur[BTILE + (nw + n * 16 + fr) * 32 + rdsw];
#pragma unroll
            for (int m = 0; m < MREP; ++m)
#pragma unroll
                for (int n = 0; n < 4; ++n) {
                    acc[m][n] = __builtin_amdgcn_mfma_f32_16x16x32_bf16(a[m],  b[n],  acc[m][n], 0, 0, 0);
                    acc[m][n] = __builtin_amdgcn_mfma_f32_16x16x32_bf16(a[m],  bl[n], acc[m][n], 0, 0, 0);
                    acc[m][n] = __builtin_amdgcn_mfma_f32_16x16x32_bf16(al[m], b[n],  acc[m][n], 0, 0, 0);
                }
        } else {
#pragma unroll
            for (int m = 0; m < MREP; ++m)
#pragma unroll
                for (int n = 0; n < 4; ++n)
                    acc[m][n] = __builtin_amdgcn_mfma_f32_16x16x32_bf16(a[m], b[n], acc[m][n], 0, 0, 0);
        }
        __syncthreads();
    }

    // ---- epilogue: D[r][c]: c = lane&15, r = (lane>>4)*4 + q
    const int fc = lane & 15;
    const int fq = (lane >> 4) * 4;

    float red[4][4];
#pragma unroll
    for (int m = 0; m < 4; ++m)
#pragma unroll
        for (int q = 0; q < 4; ++q) red[m][q] = 0.f;

    ushort* lo16 = (ushort*)aux;   // epi=3 low-half destination

#pragma unroll
    for (int n = 0; n < 4; ++n) {
        const int col = j0 + nw + n * 16 + fc;
        if (col >= Ncols) continue;
        const float bc = bias ? bias[col] : 0.f;
        const float wg = (epi == 2) ? Wg[col] : 0.f;
#pragma unroll
        for (int m = 0; m < MREP; ++m) {
            const int r0 = i0 + mw + m * 16 + fq;
            float4v v = acc[m][n];
#pragma unroll
            for (int q = 0; q < 4; ++q) {
                float x = v[q] + bc;
                const long ci = (long)bz * sC + (long)(r0 + q) * ldc + col;
                if (epi == 0) {
                    Cf[ci] = x;
                } else if (epi == 2) {
                    red[m][q] += tanhf(x) * wg;
                } else if (epi == 3) {
                    ushort h = f2bf(x);
                    C16[ci] = h;
                    lo16[ci] = f2bf(x - bf2f(h));
                } else {
                    C16[ci] = f2bf(x);
                }
            }
        }
    }
    if (epi == 2) {
#pragma unroll
        for (int m = 0; m < MREP; ++m)
#pragma unroll
            for (int q = 0; q < 4; ++q) {
                float s = red[m][q];
                s += __shfl_xor(s, 1);
                s += __shfl_xor(s, 2);
                s += __shfl_xor(s, 4);
                s += __shfl_xor(s, 8);
                if (fc == 0)
                    atomicAdd(&aux[i0 + mw + m * 16 + fq + q], s);
            }
    }
}

// ---------------------------------------------------------------------------
// Dedicated logits GEMM: 64x128 tile (MREP=2), K5 drain loop, direct epilogue.
// Measured optimum of the tile-M family: 128x128@38% occ = 248 us;
// 64x128@60% occ = 234 us; 32x128@85% occ = 328 us. Interior optimum.
// XCD swizzle: 16 M-tiles fast per XCD chunk (bijective; guard drops jt>=393).
// ---------------------------------------------------------------------------
__launch_bounds__(256, 5)
__global__ void gemm_logits(const ushort* __restrict__ A,
                            const ushort* __restrict__ B,
                            const float* __restrict__ bias,
                            float* __restrict__ C,
                            float* __restrict__ rowsum,
                            int Ncols, int K, int xcd_jtiles)
{
    constexpr int ATILE = 2048;             // 64x32 bf16 tile
    constexpr int BTILE = 4096;             // 128x32 bf16 tile
    constexpr int BUF   = ATILE + BTILE;
    __shared__ __align__(16) ushort lds[2 * BUF];   // 24 KB

    const int id = blockIdx.x;
    const int s = id >> 3;
    const int jt = (id & 7) * ((xcd_jtiles + 7) >> 3) + (s >> 4);
    const int mt = s & 15;
    if (jt >= xcd_jtiles) return;

    const int tid  = threadIdx.x;
    const int lane = tid & 63;
    const int wave = tid >> 6;
    const int mw = (wave >> 1) * 32, nw = (wave & 1) * 64;
    const int i0 = mt * 64, j0 = jt * 128;

    const int srow = tid >> 2;
    const int soff = ((tid & 3) ^ ((srow >> 1) & 3)) * 8;

    const long ar0 = i0 + srow;
    long br0 = j0 + srow;      if (br0 > Ncols - 1) br0 = Ncols - 1;
    long br1 = j0 + 64 + srow; if (br1 > Ncols - 1) br1 = Ncols - 1;

    const int NT = K >> 5;
    const int fr = lane & 15;
    const int rdsw = ((lane >> 4) ^ ((fr >> 1) & 3)) * 8;

    float4v acc[2][4];
#pragma unroll
    for (int m = 0; m < 2; ++m)
#pragma unroll
        for (int n = 0; n < 4; ++n) acc[m][n] = (float4v){0.f, 0.f, 0.f, 0.f};

    auto STAGE = [&](int buf, int kc) {
        ushort* base = lds + buf * BUF;
        gload16(&A[ar0 * K + kc + soff], base + tid * 8);
        ushort* bB = base + ATILE;
        gload16(&B[br0 * K + kc + soff], bB + tid * 8);
        gload16(&B[br1 * K + kc + soff], bB + 2048 + tid * 8);
    };

    STAGE(0, 0);
    __syncthreads();
    for (int t = 0; t < NT; ++t) {
        const int cur = t & 1;
        const ushort* Acur = lds + cur * BUF;
        const ushort* Bcur = Acur + ATILE;

        if (t + 1 < NT) STAGE(cur ^ 1, (t + 1) * 32);

        short8v a[2], b[4];
#pragma unroll
        for (int m = 0; m < 2; ++m)
            a[m] = *(const short8v*)&Acur[(mw + m * 16 + fr) * 32 + rdsw];
#pragma unroll
        for (int n = 0; n < 4; ++n)
            b[n] = *(const short8v*)&Bcur[(nw + n * 16 + fr) * 32 + rdsw];

#pragma unroll
        for (int m = 0; m < 2; ++m)
#pragma unroll
            for (int n = 0; n < 4; ++n)
                acc[m][n] = __builtin_amdgcn_mfma_f32_16x16x32_bf16(a[m], b[n], acc[m][n], 0, 0, 0);
        __syncthreads();
    }

    // ---- direct epilogue: C store + bias + exp + 16-lane shfl rowsum reduce
    const int fc = lane & 15;
    const int fq = (lane >> 4) * 4;

    float red[2][4];
#pragma unroll
    for (int m = 0; m < 2; ++m)
#pragma unroll
        for (int q = 0; q < 4; ++q) red[m][q] = 0.f;

#pragma unroll
    for (int n = 0; n < 4; ++n) {
        const int col = j0 + nw + n * 16 + fc;
        if (col >= Ncols) continue;
        const float bc = bias[col];
#pragma unroll
        for (int m = 0; m < 2; ++m) {
            const int r0 = i0 + mw + m * 16 + fq;
            float4v v = acc[m][n];
#pragma unroll
            for (int q = 0; q < 4; ++q) {
                float x = v[q] + bc;
                C[(long)(r0 + q) * Ncols + col] = x;
                red[m][q] += __expf(x);
            }
        }
    }
#pragma unroll
    for (int m = 0; m < 2; ++m)
#pragma unroll
        for (int q = 0; q < 4; ++q) {
            float sm = red[m][q];
            sm += __shfl_xor(sm, 1);
            sm += __shfl_xor(sm, 2);
            sm += __shfl_xor(sm, 4);
            sm += __shfl_xor(sm, 8);
            if (fc == 0)
                atomicAdd(&rowsum[i0 + mw + m * 16 + fq + q], sm);
        }
}

// ---- masked softmax over M=512, in place; also writes bf16 copy and zeroes
// ---- this row's rowsum/pgacc accumulators (runs before both GEMM consumers).
__global__ void softmax_rows(float* __restrict__ s, ushort* __restrict__ s16,
                             const int* __restrict__ msl,
                             float* __restrict__ rowsum, float* __restrict__ pgacc)
{
    __shared__ float red[256];
    const int row = blockIdx.x;
    const int b   = row / Tt;
    const int len = msl[b];
    float* p = s + (long)row * Mm;
    ushort* p16 = s16 + (long)row * Mm;
    const int tid = threadIdx.x;

    if (tid == 0) { rowsum[row] = 0.f; pgacc[row] = 0.f; }

    float v[2], mx = -INFINITY;
#pragma unroll
    for (int q = 0; q < 2; ++q) {
        int m = tid + q * 256;
        v[q] = (m < len) ? p[m] : -INFINITY;
        mx = fmaxf(mx, v[q]);
    }
    red[tid] = mx; __syncthreads();
    for (int off = 128; off > 0; off >>= 1) {
        if (tid < off) red[tid] = fmaxf(red[tid], red[tid + off]);
        __syncthreads();
    }
    mx = red[0]; __syncthreads();

    float e[2], sm = 0.f;
#pragma unroll
    for (int q = 0; q < 2; ++q) {
        int m = tid + q * 256;
        e[q] = (m < len) ? expf(v[q] - mx) : 0.f;
        sm += e[q];
    }
    red[tid] = sm; __syncthreads();
    for (int off = 128; off > 0; off >>= 1) {
        if (tid < off) red[tid] += red[tid + off];
        __syncthreads();
    }
    const float inv = 1.0f / red[0];
#pragma unroll
    for (int q = 0; q < 2; ++q) {
        float a = e[q] * inv;
        p[tid + q * 256] = a;
        p16[tid + q * 256] = f2bf(a);
    }
}

// ---- fused shift + copy fix-up, slice-owned -------------------------------
// grid (QS, NN): block (qq,row) owns columns [c0,c1). It (a) builds an LDS
// hash of the SLICE-LOCAL copy ids (O(len) dedupe+sum), (b) streams the
// += linv shift over its slice, then after __syncthreads (orders both the
// block's global writes and LDS) (c) RMWs each occupied slot — every p[id]
// is owned by exactly one block and was shifted by it first. No cross-block
// race; hash insert is 8x less contended than the standalone fixup.
static constexpr int QS = 8;
static constexpr int QW = DIV_UP(Vv, QS);   // 6283
__launch_bounds__(256)
__global__ void shift_fix(float* __restrict__ out, const float* __restrict__ attn,
                          const float* __restrict__ pgacc, const float* __restrict__ bg,
                          const float* __restrict__ rowsum,
                          const int* __restrict__ ids, const int* __restrict__ msl)
{
    __shared__ int   hkey[1024];
    __shared__ float hval[1024];
    const int row = blockIdx.y;
    const int qq  = blockIdx.x;
    const int b   = row / Tt;
    const int len = msl[b];
    const int tid = threadIdx.x;

    const int c0 = qq * QW;
    const int c1 = (c0 + QW < Vv) ? c0 + QW : Vv;
    const int cnt = c1 - c0;

    const float pgl = 1.0f / (1.0f + __expf(-(pgacc[row] + bg[0])));
    const float s = __logf(pgl / rowsum[row]);
    const float cc = 1.0f - pgl;

    for (int i = tid; i < 1024; i += 256) { hkey[i] = -1; hval[i] = 0.f; }
    __syncthreads();

    // (a) hash-insert slice-local ids only
    for (int m = tid; m < len; m += 256) {
        const int id = ids[(long)b * Mm + m];
        if (id < c0 || id >= c1) continue;
        const float v = attn[(long)row * Mm + m] * cc;
        unsigned h = ((unsigned)id * 2654435761u) >> 22;   // 10-bit hash
        while (true) {
            int prev = atomicCAS(&hkey[h], -1, id);
            if (prev == -1 || prev == id) { atomicAdd(&hval[h], v); break; }
            h = (h + 1) & 1023u;
        }
    }

    // (b) streaming shift of this slice
    const long base = (long)row * Vv + c0;
    float* p = out + base;
    const int mis  = (int)(((unsigned)base) & 3u);
    int head = (4 - mis) & 3;
    if (head > cnt) head = cnt;
    if (tid < head) p[tid] += s;
    const int nv = (cnt - head) >> 2;
    float4* p4 = (float4*)(p + head);
    for (int i = tid; i < nv; i += 256) {
        float4 v = p4[i];
        v.x += s; v.y += s; v.z += s; v.w += s;
        p4[i] = v;
    }
    const int t = head + nv * 4 + tid;
    if (t < cnt) p[t] += s;

    __syncthreads();   // block's global shift writes + LDS hash both complete

    // (c) fix-up: one RMW per unique slice-local id
    float* pr = out + (long)row * Vv;
    for (int i = tid; i < 1024; i += 256) {
        const int id = hkey[i];
        if (id >= 0) pr[id] = __logf(__expf(pr[id]) + hval[i]);
    }
}

extern "C" void kernel_launch(void* const* d_in, const int* in_sizes, int n_in,
                              void* d_out, int out_size, void* d_ws, size_t ws_size,
                              hipStream_t stream)
{
    const float* dec = (const float*)d_in[0];
    const float* mem = (const float*)d_in[1];
    const int*   msl = (const int*)d_in[2];
    const int*   ids = (const int*)d_in[3];
    const float* Wc  = (const float*)d_in[4];
    // d_in[5] = b_copy: per-(b,t)-constant shift of scores -> softmax-invariant; skip.
    const float* Wd  = (const float*)d_in[6];
    const float* bd  = (const float*)d_in[7];
    const float* Wg  = (const float*)d_in[8];
    const float* bg  = (const float*)d_in[9];
    const float* Wo  = (const float*)d_in[10];
    const float* bo  = (const float*)d_in[11];

    float* out = (float*)d_out;

    // ---- ws layout (~107 MB) ----
    float* ws     = (float*)d_ws;
    float* attn   = ws;                          // NN*Mm fp32 (survives to shift_fix)
    float* rowsum = attn + (size_t)NN * Mm;
    float* pgacc  = rowsum + NN;
    ushort* A16   = (ushort*)(pgacc + NN);       // dec_hi  NN*Dd
    ushort* B16   = A16 + (size_t)NN * Dd;       // W_out   Vv*Dd

    // ---- d_out doubles as scratch; everything consumed before logits GEMM ----
    ushort* S      = (ushort*)d_out;
    ushort* dec_lo = S;
    ushort* WcT_hi = dec_lo + (size_t)NN * Dd;
    ushort* WcT_lo = WcT_hi + (size_t)Dd * Dd;
    ushort* mem_hi = WcT_lo + (size_t)Dd * Dd;
    ushort* mem_lo = mem_hi + (size_t)Bb * Mm * Dd;
    ushort* memT16 = mem_lo + (size_t)Bb * Mm * Dd;
    ushort* dp_hi  = memT16 + (size_t)Bb * Mm * Dd;
    ushort* dp_lo  = dp_hi + (size_t)NN * Dd;
    ushort* Wd16   = dp_lo + (size_t)NN * Dd;
    ushort* attn16 = Wd16 + (size_t)Dd * 2 * Dd;
    ushort* ao16   = attn16 + (size_t)NN * Mm;   // attn_out bf16

    // 0. prep: all casts in one launch; transposes separate (LDS layout)
    prep_all<<<4096, 256, 0, stream>>>(dec, A16, dec_lo, mem, mem_hi, mem_lo,
                                       Wd, Wd16, Wo, B16);
    transpose_split<<<dim3(Dd/32, Dd/32, 1), 256, 0, stream>>>(Wc, WcT_hi, WcT_lo, Dd, Dd);
    transpose_split<<<dim3(Dd/32, Mm/32, Bb), 256, 0, stream>>>(mem, memT16, nullptr, Mm, Dd);

    // 1. dp = dec @ W_copy^T-form (split-bf16); epilogue writes hi/lo directly
    gemm_mx<true,2><<<dim3(Dd/128, NN/64, 1), 256, 0, stream>>>(
        A16, dec_lo, WcT_hi, WcT_lo, A16, Dd, Dd, nullptr,
        nullptr, dp_hi, (float*)dp_lo, nullptr,
        Dd, Dd, Dd, Dd, Dd, 0, 0, 0, 3);

    // 2. scores[b] = dp[b] @ mem[b]^T (split-bf16, batched)
    gemm_mx<true,2><<<dim3(Mm/128, Tt/64, Bb), 256, 0, stream>>>(
        dp_hi, dp_lo, mem_hi, mem_lo, dp_hi, Dd, Dd, nullptr,
        attn, nullptr, nullptr, nullptr,
        Mm, Dd, Dd, Dd, Mm, (long)Tt*Dd, (long)Mm*Dd, (long)Tt*Mm, 0);

    // 3. masked softmax (fp32 + bf16 outputs; zeroes rowsum/pgacc)
    softmax_rows<<<NN, 256, 0, stream>>>(attn, attn16, msl, rowsum, pgacc);

    // 4. attn_out16[b] = attn[b] @ mem[b] (bf16; feeds only p_gen)
    gemm_mx<false,2><<<dim3(Dd/128, Tt/64, Bb), 256, 0, stream>>>(
        attn16, attn16, memT16, memT16, attn16, Mm, Mm, nullptr,
        nullptr, ao16, nullptr, nullptr,
        Dd, Mm, Mm, Mm, Dd, (long)Tt*Mm, (long)Dd*Mm, (long)Tt*Dd, 4);

    // 5+6. pgacc[row] = sum_d tanh(([dec|attn_out] @ Wd^T + bd)[row,d]) * Wg[d]
    gemm_mx<false,2><<<dim3(Dd/128, NN/64, 1), 256, 0, stream>>>(
        A16, A16, Wd16, Wd16, ao16, Dd, Dd, bd,
        nullptr, nullptr, pgacc, Wg,
        Dd, 2*Dd, Dd, 2*Dd, 0, 0, 0, 0, 2);

    // 7. logits = dec @ W_out^T + b_out -> out; rowsum += sum(exp).
    //    64x128 tile (measured optimum), 5 waves/SIMD, XCD swizzle.
    gemm_logits<<<8 * 16 * DIV_UP(DIV_UP(Vv,128), 8), 256, 0, stream>>>(
        A16, B16, bo, out, rowsum, Vv, Dd, DIV_UP(Vv,128));

    // 8. fused shift + copy fix-up (slice-owned; one launch)
    shift_fix<<<dim3(QS, NN), 256, 0, stream>>>(out, attn, pgacc, bg, rowsum, ids, msl);
}